// Round 15
// baseline (347.330 us; speedup 1.0000x reference)
//
#include <hip/hip_runtime.h>

typedef __attribute__((ext_vector_type(4))) float f32x4;
typedef unsigned char u8;
typedef unsigned short u16;
typedef unsigned long long u64t;

#define BIG_NEG -1000000000.0f

static constexpr int B_  = 256;
static constexpr int SX_ = 34;
static constexpr int SY_ = 34;
static constexpr int IND = 66;   // IN_DIM
static constexpr int OP_ = 80;   // padded OUT_DIM (65 -> 80)
static constexpr int KE_ = 96;   // K-extension bytes (one-hot 66 + bias + pad)

__device__ __forceinline__ f32x4 mfma_fp8(long a, long b, f32x4 c) {
  return __builtin_amdgcn_mfma_f32_16x16x32_fp8_fp8(a, b, c, 0, 0, 0);
}
__device__ __forceinline__ float sigm(float x)  { return 1.0f / (1.0f + __expf(-x)); }
__device__ __forceinline__ float tanhx(float x) { return 2.0f * sigm(2.0f * x) - 1.0f; }
template <bool HI>
__device__ __forceinline__ unsigned pk2(float a, float b, unsigned old) {
  return __builtin_amdgcn_cvt_pk_fp8_f32(a, b, (int)old, HI);
}
// pack 8 consecutive f32 -> 8 fp8 in one long
__device__ __forceinline__ long pack8(const float* p) {
  float4 f0 = *(const float4*)p;
  float4 f1 = *(const float4*)(p + 4);
  unsigned w0 = pk2<false>(f0.x, f0.y, 0); w0 = pk2<true>(f0.z, f0.w, w0);
  unsigned w1 = pk2<false>(f1.x, f1.y, 0); w1 = pk2<true>(f1.z, f1.w, w1);
  return (long)(((u64t)w1 << 32) | (u64t)w0);
}
__device__ __forceinline__ u16 f2bf(float f) {
  unsigned b = __float_as_uint(f) + 0x8000u;
  return (u16)(b >> 16);
}
__device__ __forceinline__ float bf2f(unsigned us) {
  return __uint_as_float(us << 16);
}

// ---------------------------------------------------------------------------
// fused prep: [0,68) decode | [68,228) pad_head | [228,268) Wih-ext fp8 |
// [268,3428) conv Whh_m fp8 (grid-stride)
// w8e: fp8 [8192][96]; rows 0..2047 fwd, 2048..4095 rev, 4096..8191 mod.
//   col c<66: Wih[row][c]; c==66: bias[row]; else 0.
// ---------------------------------------------------------------------------
__global__ __launch_bounds__(256) void prep_all(
    const float* __restrict__ src, const float* __restrict__ tgt,
    int* __restrict__ tok_x, int* __restrict__ tok_y,
    const float* __restrict__ Wsub, const float* __restrict__ Wins,
    u8* __restrict__ Wcat,
    const float* __restrict__ Wihf, const float* __restrict__ bf,
    const float* __restrict__ Wihr, const float* __restrict__ br,
    const float* __restrict__ Wihm, const float* __restrict__ bm,
    u8* __restrict__ w8e,
    const float* __restrict__ Whm, u8* __restrict__ w8m) {
  const int blk = blockIdx.x;
  const int tid = threadIdx.x;

  if (blk < 68) {                       // ---- decode tokens ----
    int idx = blk * 256 + tid;
    const int half = SX_ * B_;
    const float* base = (idx < half) ? src : tgt;
    int* outp         = (idx < half) ? tok_x : tok_y;
    int k = (idx < half) ? idx : idx - half;
    const float* p = base + (size_t)k * IND;
    int tok = -1;
    for (int v = 0; v < IND; ++v) if (p[v] > 0.5f) tok = v;
    outp[k] = tok;
  } else if (blk < 228) {               // ---- pad head W -> fp8 ----
    int widx = (blk - 68) * 256 + tid;
    int row = widx >> 8;
    int wc  = widx & 255;
    int srow = row < 80 ? row : row - 80;
    const float* W = row < 80 ? Wsub : Wins;
    float f0 = 0.f, f1 = 0.f, f2 = 0.f, f3 = 0.f;
    if (srow < 65) {
      const float* p = W + (size_t)srow * 1024 + wc * 4;
      f0 = p[0]; f1 = p[1]; f2 = p[2]; f3 = p[3];
    }
    unsigned w = pk2<false>(f0, f1, 0);
    w = pk2<true>(f2, f3, w);
    ((unsigned*)Wcat)[widx] = w;
  } else if (blk < 268) {               // ---- Wih-ext fp8 ----
    int row = (blk - 228) * 256 + tid;  // 0..8191
    if (row < 8192) {
      const float* W; const float* bias; int r;
      if (row < 2048)      { W = Wihf; bias = bf; r = row; }
      else if (row < 4096) { W = Wihr; bias = br; r = row - 2048; }
      else                 { W = Wihm; bias = bm; r = row - 4096; }
      const float* wr = W + (size_t)r * IND;
      float bv = bias[r];
      unsigned* dst = (unsigned*)(w8e + (size_t)row * KE_);
#pragma unroll
      for (int w4 = 0; w4 < 24; ++w4) {
        float v0 = 0.f, v1 = 0.f, v2 = 0.f, v3 = 0.f;
        int c = w4 * 4;
        if (c + 3 < 66) {
          v0 = wr[c]; v1 = wr[c + 1]; v2 = wr[c + 2]; v3 = wr[c + 3];
        } else if (c < 68) {            // covers cols 64..67
          v0 = (c < 66) ? wr[c] : (c == 66 ? bv : 0.f);
          v1 = (c + 1 < 66) ? wr[c + 1] : (c + 1 == 66 ? bv : 0.f);
          v2 = (c + 2 < 66) ? wr[c + 2] : (c + 2 == 66 ? bv : 0.f);
          v3 = (c + 3 < 66) ? wr[c + 3] : (c + 3 == 66 ? bv : 0.f);
        }
        unsigned w2 = pk2<false>(v0, v1, 0);
        w2 = pk2<true>(v2, v3, w2);
        dst[w4] = w2;
      }
    }
  } else {                              // ---- conv Whh_m -> fp8 ----
    const int M4 = 4096 * 1024 / 4;
    int i = (blk - 268) * 256 + tid;
    int stride = 3160 * 256;
    for (; i < M4; i += stride) {
      float4 f = ((const float4*)Whm)[i];
      unsigned w3 = pk2<false>(f.x, f.y, 0);
      w3 = pk2<true>(f.z, f.w, w3);
      ((unsigned*)w8m)[i] = w3;
    }
  }
}

// ---------------------------------------------------------------------------
// persistent LSTM: 512 blocks x 256 thr, 2 blocks/CU.
// Block = (batch chunk 32) x (32 h-units x 4 gates). K extended by 96:
// one-hot(token)+bias column in LDS A-tile; Wih|bias fp8 in B ext fragments.
// No E-table gather in the epilogue.
// ---------------------------------------------------------------------------
__device__ __forceinline__ void run_lstm_mod(
    const u8* __restrict__ w8, const u8* __restrict__ w8e,
    u8* __restrict__ hall, int b0, int h0,
    unsigned* __restrict__ dom_flags, int myid,
    u8* __restrict__ alds, u8* __restrict__ hT, const u8* __restrict__ tok_small) {
  constexpr int HH = 1024;
  constexpr int NS = 32;
  constexpr int NK = 32;
  const int tid = threadIdx.x;
  const int lane = tid & 63, w = tid >> 6;
  const int lo = lane & 15, q = lane >> 4;
  constexpr int AST2 = HH + KE_ + 8;   // 1128
  const int hh = lo & 7;
  const bool hi = (lo >= 8);
  const int hu_e = h0 + w * 8 + hh;

  long breg0[NK + 3], breg1[NK + 3];
  {
    const u8* brow0 = w8 + (size_t)((lo >> 3) * HH + hu_e) * HH + q * 8;
    const u8* brow1 = w8 + (size_t)((2 + (lo >> 3)) * HH + hu_e) * HH + q * 8;
#pragma unroll
    for (int kk = 0; kk < NK; ++kk) {
      breg0[kk] = *(const long*)(brow0 + kk * 32);
      breg1[kk] = *(const long*)(brow1 + kk * 32);
    }
    const u8* e0 = w8e + (size_t)((lo >> 3) * HH + hu_e) * KE_ + q * 8;
    const u8* e1 = w8e + (size_t)((2 + (lo >> 3)) * HH + hu_e) * KE_ + q * 8;
#pragma unroll
    for (int e = 0; e < 3; ++e) {
      breg0[NK + e] = *(const long*)(e0 + e * 32);
      breg1[NK + e] = *(const long*)(e1 + e * 32);
    }
  }
  float creg[4] = {0.f, 0.f, 0.f, 0.f};

  for (int t = 0; t < 34; ++t) {
    // one-hot region (always): thread<32 owns row m=tid
    if (tid < 32) {
      u8* rowp = alds + tid * AST2 + HH;
#pragma unroll
      for (int w8i = 0; w8i < 12; ++w8i) *(u64t*)(rowp + 8 * w8i) = 0;
      int v = tok_small[t * 32 + tid];
      if (v < 66) rowp[v] = 0x38;       // fp8 e4m3 1.0
      rowp[66] = 0x38;
    }
    if (t > 0) {
      const u8* hsrc = hall + (size_t)t * (256 * HH);
      u64t tmp[16];
#pragma unroll
      for (int ii = 0; ii < 16; ++ii) {
        int idx = tid + ii * 256;
        tmp[ii] = __hip_atomic_load(
            (const u64t*)(hsrc + (size_t)(b0 + (idx >> 7)) * HH + (idx & 127) * 8),
            __ATOMIC_RELAXED, __HIP_MEMORY_SCOPE_AGENT);
      }
#pragma unroll
      for (int ii = 0; ii < 16; ++ii) {
        int idx = tid + ii * 256;
        *(u64t*)&alds[(idx >> 7) * AST2 + (idx & 127) * 8] = tmp[ii];
      }
    }
    __syncthreads();

    f32x4 acc[2][2];
#pragma unroll
    for (int mt = 0; mt < 2; ++mt) {
      acc[mt][0] = (f32x4){0.f, 0.f, 0.f, 0.f};
      acc[mt][1] = (f32x4){0.f, 0.f, 0.f, 0.f};
    }
    const u8* a0p = alds + lo * AST2 + q * 8;
    const u8* a1p = alds + (16 + lo) * AST2 + q * 8;
    if (t > 0) {
#pragma unroll
      for (int kk = 0; kk < NK; ++kk) {
        long a0 = *(const long*)(a0p + kk * 32);
        long a1 = *(const long*)(a1p + kk * 32);
        acc[0][0] = mfma_fp8(a0, breg0[kk], acc[0][0]);
        acc[0][1] = mfma_fp8(a0, breg1[kk], acc[0][1]);
        acc[1][0] = mfma_fp8(a1, breg0[kk], acc[1][0]);
        acc[1][1] = mfma_fp8(a1, breg1[kk], acc[1][1]);
      }
    }
#pragma unroll
    for (int kk = NK; kk < NK + 3; ++kk) {
      long a0 = *(const long*)(a0p + kk * 32);
      long a1 = *(const long*)(a1p + kk * 32);
      acc[0][0] = mfma_fp8(a0, breg0[kk], acc[0][0]);
      acc[0][1] = mfma_fp8(a0, breg1[kk], acc[0][1]);
      acc[1][0] = mfma_fp8(a1, breg0[kk], acc[1][0]);
      acc[1][1] = mfma_fp8(a1, breg1[kk], acc[1][1]);
    }

#pragma unroll
    for (int mt = 0; mt < 2; ++mt) {
      f32x4 t0 = acc[mt][0], t1 = acc[mt][1];
      f32x4 p0, p1;
#pragma unroll
      for (int c2 = 0; c2 < 4; ++c2) {
        p0[c2] = __shfl_xor(t0[c2], 8, 64);
        p1[c2] = __shfl_xor(t1[c2], 8, 64);
      }
#pragma unroll
      for (int rr = 0; rr < 2; ++rr) {
        int r = (hi ? 2 : 0) + rr;
        float iv = hi ? p0[r] : t0[r];
        float fv = hi ? t0[r] : p0[r];
        float gv = hi ? p1[r] : t1[r];
        float ov = hi ? t1[r] : p1[r];
        int m = mt * 16 + q * 4 + r;
        float cold = creg[mt * 2 + rr];
        float cn = sigm(fv) * cold + sigm(iv) * tanhx(gv);
        float hn = sigm(ov) * tanhx(cn);
        creg[mt * 2 + rr] = cn;
        hT[m * 32 + w * 8 + hh] = (u8)(pk2<false>(hn, hn, 0) & 0xffu);
      }
    }
    __syncthreads();

    {
      int m = tid >> 3, cc = tid & 7;
      unsigned val = *(const unsigned*)&hT[m * 32 + cc * 4];
      u8* hdst = hall + (size_t)(t + 1) * (256 * HH);
      __hip_atomic_store((unsigned*)(hdst + (size_t)(b0 + m) * HH + h0 + cc * 4),
                         val, __ATOMIC_RELAXED, __HIP_MEMORY_SCOPE_AGENT);
    }

    if (t < 33) {
      __asm__ volatile("s_waitcnt vmcnt(0)" ::: "memory");
      __syncthreads();
      unsigned tgt = (unsigned)(t + 1);
      if (tid == 0)
        __hip_atomic_store(&dom_flags[myid * 32], tgt,
                           __ATOMIC_RELAXED, __HIP_MEMORY_SCOPE_AGENT);
      if (tid < NS) {
        int spin = 0;
        for (;;) {
          unsigned v = __hip_atomic_load(&dom_flags[tid * 32],
                                         __ATOMIC_RELAXED, __HIP_MEMORY_SCOPE_AGENT);
          if (__ballot(v < tgt) == 0) break;
          __builtin_amdgcn_s_sleep(1);
          if (++spin > (1 << 17)) break;
        }
      }
      __syncthreads();
    }
  }
}

__device__ __forceinline__ void run_lstm_fr(
    const float* __restrict__ Whh, const u8* __restrict__ w8e,
    bool revr, u8* __restrict__ hall, int b0, int h0,
    unsigned* __restrict__ dom_flags, int myid,
    u8* __restrict__ alds, u8* __restrict__ hT, const u8* __restrict__ tok_small) {
  constexpr int HH = 512;
  constexpr int NS = 16;
  constexpr int NK = 16;
  const int tid = threadIdx.x;
  const int lane = tid & 63, w = tid >> 6;
  const int lo = lane & 15, q = lane >> 4;
  constexpr int AST2 = HH + KE_ + 8;   // 616
  const int hh = lo & 7;
  const bool hi = (lo >= 8);
  const int hu_e = h0 + w * 8 + hh;

  long breg0[NK + 3], breg1[NK + 3];
  {
    const float* bf0 = Whh + ((size_t)((lo >> 3) * HH + hu_e)) * HH + q * 8;
    const float* bf1 = Whh + ((size_t)((2 + (lo >> 3)) * HH + hu_e)) * HH + q * 8;
#pragma unroll
    for (int kk = 0; kk < NK; ++kk) {
      breg0[kk] = pack8(bf0 + kk * 32);
      breg1[kk] = pack8(bf1 + kk * 32);
    }
    const u8* e0 = w8e + (size_t)((lo >> 3) * HH + hu_e) * KE_ + q * 8;
    const u8* e1 = w8e + (size_t)((2 + (lo >> 3)) * HH + hu_e) * KE_ + q * 8;
#pragma unroll
    for (int e = 0; e < 3; ++e) {
      breg0[NK + e] = *(const long*)(e0 + e * 32);
      breg1[NK + e] = *(const long*)(e1 + e * 32);
    }
  }
  float creg[4] = {0.f, 0.f, 0.f, 0.f};

  for (int t = 0; t < 34; ++t) {
    int tpos = revr ? 33 - t : t;
    if (tid < 32) {
      u8* rowp = alds + tid * AST2 + HH;
#pragma unroll
      for (int w8i = 0; w8i < 12; ++w8i) *(u64t*)(rowp + 8 * w8i) = 0;
      int v = tok_small[tpos * 32 + tid];
      if (v < 66) rowp[v] = 0x38;
      rowp[66] = 0x38;
    }
    if (t > 0) {
      const u8* hsrc = hall + (size_t)t * (256 * HH);
      u64t tmp[8];
#pragma unroll
      for (int ii = 0; ii < 8; ++ii) {
        int idx = tid + ii * 256;
        tmp[ii] = __hip_atomic_load(
            (const u64t*)(hsrc + (size_t)(b0 + (idx >> 6)) * HH + (idx & 63) * 8),
            __ATOMIC_RELAXED, __HIP_MEMORY_SCOPE_AGENT);
      }
#pragma unroll
      for (int ii = 0; ii < 8; ++ii) {
        int idx = tid + ii * 256;
        *(u64t*)&alds[(idx >> 6) * AST2 + (idx & 63) * 8] = tmp[ii];
      }
    }
    __syncthreads();

    f32x4 acc[2][2];
#pragma unroll
    for (int mt = 0; mt < 2; ++mt) {
      acc[mt][0] = (f32x4){0.f, 0.f, 0.f, 0.f};
      acc[mt][1] = (f32x4){0.f, 0.f, 0.f, 0.f};
    }
    const u8* a0p = alds + lo * AST2 + q * 8;
    const u8* a1p = alds + (16 + lo) * AST2 + q * 8;
    if (t > 0) {
#pragma unroll
      for (int kk = 0; kk < NK; ++kk) {
        long a0 = *(const long*)(a0p + kk * 32);
        long a1 = *(const long*)(a1p + kk * 32);
        acc[0][0] = mfma_fp8(a0, breg0[kk], acc[0][0]);
        acc[0][1] = mfma_fp8(a0, breg1[kk], acc[0][1]);
        acc[1][0] = mfma_fp8(a1, breg0[kk], acc[1][0]);
        acc[1][1] = mfma_fp8(a1, breg1[kk], acc[1][1]);
      }
    }
#pragma unroll
    for (int kk = NK; kk < NK + 3; ++kk) {
      long a0 = *(const long*)(a0p + kk * 32);
      long a1 = *(const long*)(a1p + kk * 32);
      acc[0][0] = mfma_fp8(a0, breg0[kk], acc[0][0]);
      acc[0][1] = mfma_fp8(a0, breg1[kk], acc[0][1]);
      acc[1][0] = mfma_fp8(a1, breg0[kk], acc[1][0]);
      acc[1][1] = mfma_fp8(a1, breg1[kk], acc[1][1]);
    }

#pragma unroll
    for (int mt = 0; mt < 2; ++mt) {
      f32x4 t0 = acc[mt][0], t1 = acc[mt][1];
      f32x4 p0, p1;
#pragma unroll
      for (int c2 = 0; c2 < 4; ++c2) {
        p0[c2] = __shfl_xor(t0[c2], 8, 64);
        p1[c2] = __shfl_xor(t1[c2], 8, 64);
      }
#pragma unroll
      for (int rr = 0; rr < 2; ++rr) {
        int r = (hi ? 2 : 0) + rr;
        float iv = hi ? p0[r] : t0[r];
        float fv = hi ? t0[r] : p0[r];
        float gv = hi ? p1[r] : t1[r];
        float ov = hi ? t1[r] : p1[r];
        int m = mt * 16 + q * 4 + r;
        float cold = creg[mt * 2 + rr];
        float cn = sigm(fv) * cold + sigm(iv) * tanhx(gv);
        float hn = sigm(ov) * tanhx(cn);
        creg[mt * 2 + rr] = cn;
        hT[m * 32 + w * 8 + hh] = (u8)(pk2<false>(hn, hn, 0) & 0xffu);
      }
    }
    __syncthreads();

    {
      int m = tid >> 3, cc = tid & 7;
      unsigned val = *(const unsigned*)&hT[m * 32 + cc * 4];
      u8* hdst = hall + (size_t)(t + 1) * (256 * HH);
      __hip_atomic_store((unsigned*)(hdst + (size_t)(b0 + m) * HH + h0 + cc * 4),
                         val, __ATOMIC_RELAXED, __HIP_MEMORY_SCOPE_AGENT);
    }

    if (t < 33) {
      __asm__ volatile("s_waitcnt vmcnt(0)" ::: "memory");
      __syncthreads();
      unsigned tgt = (unsigned)(t + 1);
      if (tid == 0)
        __hip_atomic_store(&dom_flags[myid * 32], tgt,
                           __ATOMIC_RELAXED, __HIP_MEMORY_SCOPE_AGENT);
      if (tid < NS) {
        int spin = 0;
        for (;;) {
          unsigned v = __hip_atomic_load(&dom_flags[tid * 32],
                                         __ATOMIC_RELAXED, __HIP_MEMORY_SCOPE_AGENT);
          if (__ballot(v < tgt) == 0) break;
          __builtin_amdgcn_s_sleep(1);
          if (++spin > (1 << 17)) break;
        }
      }
      __syncthreads();
    }
  }
}

__global__ __launch_bounds__(256, 2) void lstm_persist(
    const int* __restrict__ tok_x, const int* __restrict__ tok_y,
    const float* __restrict__ Whh_f, const float* __restrict__ Whh_r,
    const u8* __restrict__ w8_m, const u8* __restrict__ w8e,
    u8* __restrict__ fwd_all, u8* __restrict__ rev_all, u8* __restrict__ y_all,
    unsigned* __restrict__ flags) {
  __shared__ u8 alds[32 * 1128];       // mod stride 1128; fr uses 616
  __shared__ u8 hT[32 * 32];
  __shared__ u8 tok_small[34 * 32];

  const int b = blockIdx.x;
  int role, c, s;
  if (b < 256)      { role = 2; c = b >> 5; s = b & 31; }          // mod: 256
  else if (b < 384) { int l = b - 256; role = 0; c = l >> 4; s = l & 15; }  // fwd
  else              { int l = b - 384; role = 1; c = l >> 4; s = l & 15; }  // rev

  u8* hall        = role == 0 ? fwd_all : role == 1 ? rev_all : y_all;
  const int* tokg = (role == 2) ? tok_y : tok_x;
  const int b0 = c * 32;
  const int h0 = s * 32;
  const int dom0 = (role == 2) ? c * 32 : (role == 0) ? 256 + c * 16 : 384 + c * 16;

  for (int i = threadIdx.x; i < 34 * 32; i += 256) {
    int t2 = i >> 5, m = i & 31;
    int tk = tokg[t2 * 256 + b0 + m];
    tok_small[i] = (u8)(tk < 0 ? 66 : tk);
  }
  __syncthreads();

  unsigned* dom_flags = flags + dom0 * 32;
  if (role == 2)
    run_lstm_mod(w8_m, w8e + (size_t)4096 * KE_ * 1, hall, b0, h0, dom_flags, s,
                 alds, hT, tok_small);
  else if (role == 0)
    run_lstm_fr(Whh_f, w8e, false, hall, b0, h0, dom_flags, s, alds, hT, tok_small);
  else
    run_lstm_fr(Whh_r, w8e + (size_t)2048 * KE_, true, hall, b0, h0, dom_flags, s,
                alds, hT, tok_small);
}

// ---------------------------------------------------------------------------
// head: lx (f32) and ly (bf16). 272 blocks x 256 thr; 64 rows/block.
// ---------------------------------------------------------------------------
__global__ __launch_bounds__(256, 1) void head_kernel(
    const u8* __restrict__ fwd_all, const u8* __restrict__ rev_all,
    const u8* __restrict__ y_all, const u8* __restrict__ Wcat,
    const float* __restrict__ b_sub, const float* __restrict__ b_ins,
    float* __restrict__ lx_sub, float* __restrict__ lx_ins,
    u16* __restrict__ ly_sub, u16* __restrict__ ly_ins) {
  __shared__ u8 wq[160 * 264];
  const int lane = threadIdx.x & 63, wave = threadIdx.x >> 6;
  const int lo = lane & 15, q = lane >> 4;
  int blk = blockIdx.x;
  bool yside = (blk >= 136);
  int mb = yside ? blk - 136 : blk;
  int ij = mb >> 2;
  int bbase = (mb & 3) * 64;

  f32x4 acc[10];
#pragma unroll
  for (int nn = 0; nn < 10; ++nn) acc[nn] = (f32x4){0.f,0.f,0.f,0.f};

  for (int qk = 0; qk < 4; ++qk) {
    long aA[8];
    {
      int row = bbase + wave * 16 + lo;
      const u8* ab;
      if (yside)
        ab = y_all + ((size_t)(ij + 1) * 256 + row) * 1024 + qk * 256 + q * 8;
      else if (qk < 2)
        ab = fwd_all + ((size_t)(ij + 1) * 256 + row) * 512 + qk * 256 + q * 8;
      else
        ab = rev_all + ((size_t)(34 - ij) * 256 + row) * 512 + (qk - 2) * 256 + q * 8;
#pragma unroll
      for (int ki = 0; ki < 8; ++ki) aA[ki] = *(const long*)(ab + ki * 32);
    }

    for (int c8 = threadIdx.x; c8 < 160 * 32; c8 += 256) {
      int row = c8 >> 5, col = (c8 & 31) << 3;
      *(long*)&wq[row * 264 + col] =
          *(const long*)&Wcat[(size_t)row * 1024 + qk * 256 + col];
    }
    __syncthreads();

#pragma unroll
    for (int ki = 0; ki < 8; ++ki) {
#pragma unroll
      for (int nn = 0; nn < 10; ++nn) {
        long bf = *(const long*)&wq[(nn * 16 + lo) * 264 + ki * 32 + q * 8];
        acc[nn] = mfma_fp8(aA[ki], bf, acc[nn]);
      }
    }
    __syncthreads();
  }

#pragma unroll
  for (int nn = 0; nn < 10; ++nn) {
    bool is_sub = (nn < 5);
    int n = (is_sub ? nn : nn - 5) * 16 + lo;
    if (yside) {
      float bias = (n < 65) ? (is_sub ? b_sub[n] : b_ins[n]) : 0.0f;
      u16* dst = is_sub ? ly_sub : ly_ins;
#pragma unroll
      for (int r = 0; r < 4; ++r) {
        int b = bbase + wave * 16 + q * 4 + r;
        dst[((size_t)ij * 256 + b) * OP_ + n] = f2bf(acc[nn][r] + bias);
      }
    } else {
      float* dst = is_sub ? lx_sub : lx_ins;
#pragma unroll
      for (int r = 0; r < 4; ++r) {
        int b = bbase + wave * 16 + q * 4 + r;
        dst[((size_t)ij * 256 + b) * OP_ + n] = acc[nn][r];
      }
    }
  }
}

// ---------------------------------------------------------------------------
// pair: grid 272 = head{sub,ins} x 34 i x 4 b-chunks; X (f32) in regs,
// Y read as bf16 (half the hot traffic).
// ---------------------------------------------------------------------------
__global__ __launch_bounds__(256, 1) void pair_kernel(
    const int* __restrict__ tok_x, const int* __restrict__ tok_y,
    const float* __restrict__ lx_sub, const float* __restrict__ lx_ins,
    const u16* __restrict__ ly_sub, const u16* __restrict__ ly_ins,
    float* __restrict__ out) {
  const int hsel = blockIdx.x >= 136;
  const int rem = hsel ? blockIdx.x - 136 : blockIdx.x;
  const int i = rem >> 2;
  const int bc = rem & 3;
  const int jq = threadIdx.x >> 6;
  const int bl = threadIdx.x & 63;
  const int b = bc * 64 + bl;
  const size_t CH = (size_t)SX_ * SY_ * B_;
  const float* lx = hsel ? lx_ins : lx_sub;
  const u16* ly = hsel ? ly_ins : ly_sub;
  float* outA = out + (hsel ? 0 : CH);
  float* outB = out + (hsel ? 2 * CH : 3 * CH);

  float4 X[17];
  {
    const float4* ps = (const float4*)(lx + ((size_t)i * 256 + b) * OP_);
#pragma unroll
    for (int q = 0; q < 17; ++q) X[q] = ps[q];
  }
  int tx = tok_x[i * 256 + b];

  for (int j = jq; j < 34; j += 4) {
    size_t obase = ((size_t)i * SY_ + j) * 256 + b;
    bool dead = (j == SY_ - 1) || (tx < 0);
    if (!dead) {
      int ty = tok_y[j * 256 + b];
      if (ty < 0) dead = true;
    }
    if (dead) {
      outA[obase] = BIG_NEG;
      outB[obase] = BIG_NEG;
      continue;
    }
    int tn = tok_y[(j + 1) * 256 + b];
    bool ins_ok = (tn != 65);
    int sym = (tn >= 0 && tn < 64) ? tn : -1;

    float v[68];
    {
      const u64t* py = (const u64t*)(ly + ((size_t)j * 256 + b) * OP_);
#pragma unroll
      for (int q2 = 0; q2 < 17; ++q2) {
        u64t y = py[q2];
        v[4 * q2 + 0] = X[q2].x + bf2f((unsigned)(y & 0xffffu));
        v[4 * q2 + 1] = X[q2].y + bf2f((unsigned)((y >> 16) & 0xffffu));
        v[4 * q2 + 2] = X[q2].z + bf2f((unsigned)((y >> 32) & 0xffffu));
        v[4 * q2 + 3] = X[q2].w + bf2f((unsigned)(y >> 48));
      }
    }
    float m = v[0];
#pragma unroll
    for (int o = 1; o < 65; ++o) m = fmaxf(m, v[o]);
    float s = 0.0f, vsl = 0.0f;
#pragma unroll
    for (int o = 0; o < 65; ++o) {
      s += __expf(v[o] - m);
      if (o < 64) vsl = (o == sym) ? v[o] : vsl;
    }
    float logZ = m + __logf(s);
    float valB = v[64] - logZ;
    float valA = (sym >= 0) ? (vsl - logZ) : 0.0f;
    outA[obase] = ins_ok ? valA : BIG_NEG;
    outB[obase] = valB;
  }
}

// ---------------------------------------------------------------------------
// launch
// ---------------------------------------------------------------------------
extern "C" void kernel_launch(void* const* d_in, const int* in_sizes, int n_in,
                              void* d_out, int out_size, void* d_ws, size_t ws_size,
                              hipStream_t stream) {
  const float* sources = (const float*)d_in[0];
  const float* targets = (const float*)d_in[1];
  const float* Wih_f = (const float*)d_in[2];
  const float* Whh_f = (const float*)d_in[3];
  const float* b_f   = (const float*)d_in[4];
  const float* Wih_r = (const float*)d_in[5];
  const float* Whh_r = (const float*)d_in[6];
  const float* b_r   = (const float*)d_in[7];
  const float* Wih_m = (const float*)d_in[8];
  const float* Whh_m = (const float*)d_in[9];
  const float* b_m   = (const float*)d_in[10];
  const float* W_sub = (const float*)d_in[11];
  const float* b_sub = (const float*)d_in[12];
  const float* W_ins = (const float*)d_in[13];
  const float* b_ins = (const float*)d_in[14];
  float* out = (float*)d_out;

  char* w = (char*)d_ws;
  constexpr size_t FLAG_SZ = 512 * 32 * 4;
  constexpr size_t TOK_SZ  = (size_t)SX_ * B_ * 4;
  constexpr size_t WCAT_SZ = (size_t)160 * 1024;
  constexpr size_t W8M_SZ  = (size_t)4096 * 1024;
  constexpr size_t W8E_SZ  = (size_t)8192 * KE_;
  constexpr size_t LX_SZ   = (size_t)SX_ * B_ * OP_ * 4;
  constexpr size_t LY_SZ   = (size_t)SX_ * B_ * OP_ * 2;
  constexpr size_t HF_SZ   = (size_t)35 * B_ * 512;
  constexpr size_t HM_SZ   = (size_t)35 * B_ * 1024;

  size_t off = 0;
  unsigned* flags = (unsigned*)(w + off); off += FLAG_SZ;
  int*  tok_x   = (int*)(w + off);  off += TOK_SZ;
  int*  tok_y   = (int*)(w + off);  off += TOK_SZ;
  off = (off + 255) & ~(size_t)255;
  u8*   Wcat    = (u8*)(w + off);   off += WCAT_SZ;
  u8*   w8_m    = (u8*)(w + off);   off += W8M_SZ;
  u8*   w8e     = (u8*)(w + off);   off += W8E_SZ;
  float* lx_sub = (float*)(w + off); off += LX_SZ;
  float* lx_ins = (float*)(w + off); off += LX_SZ;
  u16*  ly_sub  = (u16*)(w + off);  off += LY_SZ;
  u16*  ly_ins  = (u16*)(w + off);  off += LY_SZ;
  off = (off + 255) & ~(size_t)255;
  u8* fwd_all   = (u8*)(w + off);   off += HF_SZ;
  u8* rev_all   = (u8*)(w + off);   off += HF_SZ;
  u8* y_all     = (u8*)(w + off);   off += HM_SZ;
  (void)ws_size; (void)in_sizes; (void)n_in; (void)out_size;

  (void)hipMemsetAsync(flags, 0, FLAG_SZ, stream);

  prep_all<<<3428, 256, 0, stream>>>(
      sources, targets, tok_x, tok_y,
      W_sub, W_ins, Wcat,
      Wih_f, b_f, Wih_r, b_r, Wih_m, b_m, w8e,
      Whh_m, w8_m);

  lstm_persist<<<512, 256, 0, stream>>>(
      tok_x, tok_y,
      Whh_f, Whh_r,
      w8_m, w8e,
      fwd_all, rev_all, y_all, flags);

  head_kernel<<<272, 256, 0, stream>>>(fwd_all, rev_all, y_all, Wcat,
                                       b_sub, b_ins, lx_sub, lx_ins, ly_sub, ly_ins);

  pair_kernel<<<272, 256, 0, stream>>>(tok_x, tok_y, lx_sub, lx_ins,
                                       ly_sub, ly_ins, out);
}